// Round 8
// baseline (277.425 us; speedup 1.0000x reference)
//
#include <hip/hip_runtime.h>
#include <stdint.h>

#define NDIM 512
#define HEADS 8
#define DHEAD 64
#define NSEQ 4096
#define BATCH 8
#define ROWS (BATCH * NSEQ)   // 32768
#define QKVN (3 * NDIM)       // 1536
// xnT blocked layout: elem (c, n) at ((n>>6)*512 + c)*64 + (n&63)
#define CHUNK_STRIDE 32768    // 512 c * 64 n elems per n-chunk

typedef unsigned short ushort_t;
typedef __bf16 bf16x8 __attribute__((ext_vector_type(8)));
typedef float f32x4 __attribute__((ext_vector_type(4)));
typedef unsigned short u16x8 __attribute__((ext_vector_type(8)));
typedef unsigned short u16x4 __attribute__((ext_vector_type(4)));

__device__ __forceinline__ ushort_t f2bf(float f) {
  union { float f; uint32_t u; } v; v.f = f;
  uint32_t r = (v.u + 0x7FFFu + ((v.u >> 16) & 1u)) >> 16;
  return (ushort_t)r;
}
__device__ __forceinline__ float bf2f(ushort_t h) {
  union { uint32_t u; float f; } v; v.u = ((uint32_t)h) << 16;
  return v.f;
}

__device__ __forceinline__ void gload_lds16(const void* g, void* l) {
  __builtin_amdgcn_global_load_lds(
      (__attribute__((address_space(1))) void*)(g),
      (__attribute__((address_space(3))) void*)(l), 16, 0, 0);
}

// ---------------------------------------------------------------------------
// K1: fused prep. Grid layout (256 threads each):
//   [0,8192)       rmsnorm (4 rows/block) -> xn bf16
//   [8192,8704)    wqkT transpose: w_qkv cols 0..1023 -> wqkT[1024][512]
//   [8704,8960)    woutT transpose: w_out -> woutT[512][512]
//   [8960,9088)    wv cast: w_qkv cols 1024..1535 -> wv[512 c][512 hE] bf16
//   [9088,9600)    zero S f32 (8 MB)
// ---------------------------------------------------------------------------
__global__ __launch_bounds__(256) void prep_rms_k(const float* __restrict__ x,
                                                  const float* __restrict__ gamma,
                                                  ushort_t* __restrict__ xn,
                                                  const float* __restrict__ w_qkv,
                                                  const float* __restrict__ w_out,
                                                  ushort_t* __restrict__ wqkT,
                                                  ushort_t* __restrict__ woutT,
                                                  ushort_t* __restrict__ wv,
                                                  float* __restrict__ S) {
  __shared__ float tile[32][33];
  int bid = blockIdx.x;
  int t = threadIdx.x;
  if (bid < 8192) {
    int wave = t >> 6, lane = t & 63;
    size_t row = (size_t)bid * 4 + wave;
    const float4* xr = (const float4*)(x + row * NDIM);
    float4 v0 = xr[lane * 2], v1 = xr[lane * 2 + 1];
    float s = v0.x*v0.x + v0.y*v0.y + v0.z*v0.z + v0.w*v0.w
            + v1.x*v1.x + v1.y*v1.y + v1.z*v1.z + v1.w*v1.w;
#pragma unroll
    for (int off = 32; off; off >>= 1) s += __shfl_xor(s, off, 64);
    float scale = 22.627416997969522f / fmaxf(sqrtf(s), 1e-12f);
    const float4* gr = (const float4*)gamma;
    float4 g0 = gr[lane * 2], g1 = gr[lane * 2 + 1];
    u16x8 o;
    o[0] = f2bf(v0.x * scale * g0.x);
    o[1] = f2bf(v0.y * scale * g0.y);
    o[2] = f2bf(v0.z * scale * g0.z);
    o[3] = f2bf(v0.w * scale * g0.w);
    o[4] = f2bf(v1.x * scale * g1.x);
    o[5] = f2bf(v1.y * scale * g1.y);
    o[6] = f2bf(v1.z * scale * g1.z);
    o[7] = f2bf(v1.w * scale * g1.w);
    *(u16x8*)(xn + row * NDIM + lane * 8) = o;
  } else if (bid < 8960) {
    // transpose+cast 32x32 tiles
    int id = bid - 8192;
    const float* src;
    ushort_t* dst;
    int srcStride, ni, ki;
    if (id < 512) { ni = id & 31; ki = id >> 5; src = w_qkv; dst = wqkT; srcStride = QKVN; }
    else { id -= 512; ni = id & 15; ki = id >> 4; src = w_out; dst = woutT; srcStride = NDIM; }
    int tr = t >> 3;
    int tc = (t & 7) * 4;
    float4 v = *(const float4*)(src + (size_t)(ki * 32 + tr) * srcStride + ni * 32 + tc);
    tile[tr][tc] = v.x; tile[tr][tc + 1] = v.y; tile[tr][tc + 2] = v.z; tile[tr][tc + 3] = v.w;
    __syncthreads();
    u16x4 o;
    o[0] = f2bf(tile[tc + 0][tr]);
    o[1] = f2bf(tile[tc + 1][tr]);
    o[2] = f2bf(tile[tc + 2][tr]);
    o[3] = f2bf(tile[tc + 3][tr]);
    *(u16x4*)(dst + (size_t)(ni * 32 + tr) * NDIM + ki * 32 + tc) = o;
  } else if (bid < 9088) {
    // wv cast: wv[c][j] = bf16(w_qkv[c][1024 + j])
    int id = bid - 8960;
    int f = id * 2048 + t * 8;
    int c = f >> 9, j = f & 511;
    float4 u0 = *(const float4*)(w_qkv + (size_t)c * QKVN + 1024 + j);
    float4 u1 = *(const float4*)(w_qkv + (size_t)c * QKVN + 1024 + j + 4);
    u16x8 o;
    o[0] = f2bf(u0.x); o[1] = f2bf(u0.y); o[2] = f2bf(u0.z); o[3] = f2bf(u0.w);
    o[4] = f2bf(u1.x); o[5] = f2bf(u1.y); o[6] = f2bf(u1.z); o[7] = f2bf(u1.w);
    *(u16x8*)(wv + (size_t)c * 512 + j) = o;
  } else {
    // zero S (8 MB f32)
    int id = bid - 9088;   // 0..511, 4096 f32 per block
    f32x4 z = {};
#pragma unroll
    for (int i = 0; i < 4; ++i)
      *(f32x4*)(S + (size_t)id * 4096 + i * 1024 + t * 4) = z;
  }
}

// ---------------------------------------------------------------------------
// K2: blocked transpose: xnTb[(n>>6)*512 + c][n&63] = xn[n][c]
// One block per (n-chunk, c-tile-of-64): writes contiguous 8 KB.
// ---------------------------------------------------------------------------
__global__ __launch_bounds__(256) void xnt_k(const ushort_t* __restrict__ xn,
                                             ushort_t* __restrict__ xnTb) {
  __shared__ ushort_t tile[64 * 72];
  int nc = blockIdx.x & 511, ct = blockIdx.x >> 9;
  int n0 = nc * 64, c0 = ct * 64;
  int t = threadIdx.x;
  int row = t >> 2, cc = (t & 3) * 16;
  *(u16x8*)(tile + row * 72 + cc)     = *(const u16x8*)(xn + (size_t)(n0 + row) * NDIM + c0 + cc);
  *(u16x8*)(tile + row * 72 + cc + 8) = *(const u16x8*)(xn + (size_t)(n0 + row) * NDIM + c0 + cc + 8);
  __syncthreads();
  int oc = t >> 2, on = (t & 3) * 16;
  u16x8 a, b;
#pragma unroll
  for (int i = 0; i < 8; ++i) {
    a[i] = tile[(on + i) * 72 + oc];
    b[i] = tile[(on + 8 + i) * 72 + oc];
  }
  ushort_t* dst = xnTb + ((size_t)nc * 512 + c0 + oc) * 64;
  *(u16x8*)(dst + on)     = a;
  *(u16x8*)(dst + on + 8) = b;
}

// ---------------------------------------------------------------------------
// K3: syrk, R0-style 128x128 tile, 256 threads, 32 KB LDS -> ~5 blocks/CU.
// Grid 512 = b(8) x [ks(4) x mt(4) x nt(4) ... 16 tiles], K=1024 per block,
// contraction over n of blocked xnTb; f32 atomicAdd epilogue (K-split 4).
// ---------------------------------------------------------------------------
__global__ __launch_bounds__(256) void syrk_k(const ushort_t* __restrict__ xnTb,
                                              float* __restrict__ S) {
  __shared__ __align__(16) ushort_t As[8192];   // [128][64] swizzled, 16 KB
  __shared__ __align__(16) ushort_t Bs[8192];
  const int flat = blockIdx.x;       // 512
  const int b = flat & 7;
  const int local = flat >> 3;       // 0..63
  const int ks = local & 3;
  const int tl = local >> 2;         // 0..15
  const int mt = tl >> 2, nt = tl & 3;
  const int m0 = mt * 128, n0 = nt * 128;
  const int tid = threadIdx.x, lane = tid & 63, wave = tid >> 6;
  const int srow = lane >> 3;
  const int scol = ((lane & 7) ^ srow) * 16;
  const int r = lane & 15, q = lane >> 4;
  const int wm = (wave >> 1) * 64, wn = (wave & 1) * 64;
  // 16 n-chunks of 64 (=1024 n) per (b, ks)
  const ushort_t* base = xnTb + (size_t)(b * 64 + ks * 16) * CHUNK_STRIDE;

  f32x4 acc[4][4] = {};
  for (int t2 = 0; t2 < 16; ++t2) {
    const ushort_t* kb_ = base + (size_t)t2 * CHUNK_STRIDE;
    __syncthreads();
#pragma unroll
    for (int c = 0; c < 4; ++c) {
      int g = wave * 4 + c;
      gload_lds16((const char*)(kb_ + (size_t)(m0 + g * 8 + srow) * 64) + scol,
                  (char*)(As + g * 512));
      gload_lds16((const char*)(kb_ + (size_t)(n0 + g * 8 + srow) * 64) + scol,
                  (char*)(Bs + g * 512));
    }
    __syncthreads();
#pragma unroll
    for (int ph = 0; ph < 2; ++ph) {
      const int kb = ph * 4 + q;
      bf16x8 af[4], bfr[4];
#pragma unroll
      for (int i = 0; i < 4; ++i) {
        int row = wm + i * 16 + r;
        af[i] = *(const bf16x8*)(const void*)(As + row * 64 + ((kb ^ (row & 7)) << 3));
      }
#pragma unroll
      for (int j = 0; j < 4; ++j) {
        int row = wn + j * 16 + r;
        bfr[j] = *(const bf16x8*)(const void*)(Bs + row * 64 + ((kb ^ (row & 7)) << 3));
      }
#pragma unroll
      for (int i = 0; i < 4; ++i)
#pragma unroll
        for (int j = 0; j < 4; ++j)
          acc[i][j] = __builtin_amdgcn_mfma_f32_16x16x32_bf16(af[i], bfr[j], acc[i][j], 0, 0, 0);
    }
  }
  float* Sb = S + (size_t)b * 262144;
#pragma unroll
  for (int i = 0; i < 4; ++i)
#pragma unroll
    for (int j = 0; j < 4; ++j)
#pragma unroll
      for (int v = 0; v < 4; ++v)
        atomicAdd(&Sb[(size_t)(m0 + wm + i * 16 + q * 4 + v) * 512 + n0 + wn + j * 16 + r],
                  acc[i][j][v]);
}

// ---------------------------------------------------------------------------
// K4: PT[b][kd][c] = sum_c' wqkT[kd][c'] * S_b[c][c']   (R4 known-good version)
// Tiles 128x128, 256 threads, simple double-barrier loop. B staged f32->bf16.
// ---------------------------------------------------------------------------
__global__ __launch_bounds__(256) void pt_k(const ushort_t* __restrict__ wqkT,
                                            const float* __restrict__ S,
                                            ushort_t* __restrict__ PT) {
  __shared__ __align__(16) ushort_t As[8192];   // [128][64] swizzled
  __shared__ __align__(16) ushort_t Bs[8192];
  const int flat = blockIdx.x;        // 256 = b(8) x mt(8) x nt(4)
  const int b = flat & 7;
  const int local = flat >> 3;
  const int mt = local >> 2, nt = local & 3;
  const int m0 = mt * 128, n0 = nt * 128;
  const int tid = threadIdx.x;
  const int lane = tid & 63, wave = tid >> 6;
  const int srow = lane >> 3;
  const int scol = ((lane & 7) ^ srow) * 16;
  const int r = lane & 15, q = lane >> 4;
  const int wm = (wave >> 1) * 64, wn = (wave & 1) * 64;
  const float* Sb = S + (size_t)b * 262144;
  const int brow = tid >> 1, bhalf = tid & 1;

  f32x4 acc[4][4] = {};
  for (int k0 = 0; k0 < 512; k0 += 64) {
    __syncthreads();
#pragma unroll
    for (int c = 0; c < 4; ++c) {
      int g = wave * 4 + c;
      gload_lds16((const char*)(wqkT + (size_t)(m0 + g * 8 + srow) * 512 + k0) + scol,
                  (char*)(As + g * 512));
    }
    {
      const float* src = Sb + (size_t)(n0 + brow) * 512 + k0 + bhalf * 32;
#pragma unroll
      for (int u = 0; u < 4; ++u) {
        float4 f0 = *(const float4*)(src + u * 8);
        float4 f1 = *(const float4*)(src + u * 8 + 4);
        u16x8 o;
        o[0] = f2bf(f0.x); o[1] = f2bf(f0.y); o[2] = f2bf(f0.z); o[3] = f2bf(f0.w);
        o[4] = f2bf(f1.x); o[5] = f2bf(f1.y); o[6] = f2bf(f1.z); o[7] = f2bf(f1.w);
        int c8 = bhalf * 4 + u;
        *(u16x8*)(Bs + brow * 64 + ((c8 ^ (brow & 7)) << 3)) = o;
      }
    }
    __syncthreads();
#pragma unroll
    for (int ph = 0; ph < 2; ++ph) {
      const int kb = ph * 4 + q;
      bf16x8 af[4], bfr[4];
#pragma unroll
      for (int i = 0; i < 4; ++i) {
        int row = wm + i * 16 + r;
        af[i] = *(const bf16x8*)(const void*)(As + row * 64 + ((kb ^ (row & 7)) << 3));
      }
#pragma unroll
      for (int j = 0; j < 4; ++j) {
        int row = wn + j * 16 + r;
        bfr[j] = *(const bf16x8*)(const void*)(Bs + row * 64 + ((kb ^ (row & 7)) << 3));
      }
#pragma unroll
      for (int i = 0; i < 4; ++i)
#pragma unroll
        for (int j = 0; j < 4; ++j)
          acc[i][j] = __builtin_amdgcn_mfma_f32_16x16x32_bf16(af[i], bfr[j], acc[i][j], 0, 0, 0);
    }
  }
  ushort_t* dst = PT + (size_t)b * 524288;
#pragma unroll
  for (int i = 0; i < 4; ++i)
#pragma unroll
    for (int j = 0; j < 4; ++j)
#pragma unroll
      for (int v = 0; v < 4; ++v)
        dst[(size_t)(m0 + wm + i * 16 + q * 4 + v) * 512 + n0 + wn + j * 16 + r] =
            f2bf(acc[i][j][v]);
}

// ---------------------------------------------------------------------------
// K5a: per (b,h): G = Wq^T S Wk via wqkT/PT rows, norms via rowdots,
// softmax over e, write attnT[bh][e][d] bf16.
// ---------------------------------------------------------------------------
__global__ __launch_bounds__(256) void gsm_k(const ushort_t* __restrict__ wqkT,
                                             const ushort_t* __restrict__ PT,
                                             const float* __restrict__ temp,
                                             ushort_t* __restrict__ attnT) {
  int bh = blockIdx.x;
  int b = bh >> 3, h = bh & 7;
  int hb = h * 64;
  __shared__ float Gf[64][68];
  __shared__ float kq[128];
  int t = threadIdx.x, lane = t & 63, wave = t >> 6;
  int r = lane & 15, q = lane >> 4;
  const ushort_t* ptb = PT + (size_t)b * 524288;

  f32x4 acc[4] = {};
  const ushort_t* arow = wqkT + (size_t)(hb + wave * 16 + r) * 512;
#pragma unroll
  for (int kk = 0; kk < 512; kk += 32) {
    bf16x8 a = *(const bf16x8*)(arow + kk + q * 8);
#pragma unroll
    for (int j = 0; j < 4; ++j) {
      bf16x8 bb = *(const bf16x8*)(ptb + (size_t)(512 + hb + j * 16 + r) * 512 + kk + q * 8);
      acc[j] = __builtin_amdgcn_mfma_f32_16x16x32_bf16(a, bb, acc[j], 0, 0, 0);
    }
  }
#pragma unroll
  for (int j = 0; j < 4; ++j)
#pragma unroll
    for (int v = 0; v < 4; ++v)
      Gf[wave * 16 + q * 4 + v][j * 16 + r] = acc[j][v];
  if (t < 128) {
    int row = (t < 64) ? (hb + t) : (512 + hb + (t - 64));
    const ushort_t* wr = wqkT + (size_t)row * 512;
    const ushort_t* pr = ptb + (size_t)row * 512;
    float s = 0.f;
    for (int i = 0; i < 512; i += 8) {
      u16x8 wa = *(const u16x8*)(wr + i);
      u16x8 pa = *(const u16x8*)(pr + i);
#pragma unroll
      for (int e2 = 0; e2 < 8; ++e2) s += bf2f(wa[e2]) * bf2f(pa[e2]);
    }
    kq[t] = s;
  }
  __syncthreads();

  int d = t >> 2, eg = (t & 3) * 16;
  float qn = fmaxf(sqrtf(kq[d]), 1e-12f);
  float scale = 8.0f * expf(temp[h]) / qn;
  float row[16];
#pragma unroll
  for (int k = 0; k < 16; ++k)
    row[k] = Gf[d][eg + k] * scale / fmaxf(sqrtf(kq[64 + eg + k]), 1e-12f);
  float mx = -1e30f;
#pragma unroll
  for (int k = 0; k < 16; ++k) mx = fmaxf(mx, row[k]);
  mx = fmaxf(mx, __shfl_xor(mx, 1, 64));
  mx = fmaxf(mx, __shfl_xor(mx, 2, 64));
  float s = 0.f;
#pragma unroll
  for (int k = 0; k < 16; ++k) { row[k] = expf(row[k] - mx); s += row[k]; }
  s += __shfl_xor(s, 1, 64);
  s += __shfl_xor(s, 2, 64);
  float inv = 1.0f / s;
#pragma unroll
  for (int k = 0; k < 16; ++k)
    attnT[(size_t)bh * 4096 + (eg + k) * 64 + d] = f2bf(row[k] * inv);
}

// ---------------------------------------------------------------------------
// K5b: MT[b][c'][c] = sum_h sum_e (sum_d woutT[c'][hd]*attnT[bh][e][d]) * wv[c][hE]
// ---------------------------------------------------------------------------
__global__ __launch_bounds__(256) void atmt_k(const ushort_t* __restrict__ woutT,
                                              const ushort_t* __restrict__ attnT,
                                              const ushort_t* __restrict__ wv,
                                              ushort_t* __restrict__ MT) {
  __shared__ ushort_t at[128 * 72];
  const int flat = blockIdx.x;     // 128
  const int b = flat & 7;
  const int local = flat >> 3;     // 0..15
  const int mq = local >> 2, nq = local & 3;
  int t = threadIdx.x, lane = t & 63, w = t >> 6;
  int r = lane & 15, q = lane >> 4;
  int wm2 = (w >> 1) * 64, wn2 = (w & 1) * 64;
  f32x4 acc2[4][4] = {};
  for (int h = 0; h < 8; ++h) {
    int hb = h * 64;
    const ushort_t* atn = attnT + (size_t)(b * 8 + h) * 4096;
    f32x4 acc1[2][4] = {};
#pragma unroll
    for (int kk = 0; kk < 64; kk += 32) {
      bf16x8 a[2], bb[4];
#pragma unroll
      for (int i = 0; i < 2; ++i)
        a[i] = *(const bf16x8*)(woutT + (size_t)(mq * 128 + w * 32 + i * 16 + r) * 512 + hb + kk + q * 8);
#pragma unroll
      for (int j = 0; j < 4; ++j)
        bb[j] = *(const bf16x8*)(atn + (j * 16 + r) * 64 + kk + q * 8);
#pragma unroll
      for (int i = 0; i < 2; ++i)
#pragma unroll
        for (int j = 0; j < 4; ++j)
          acc1[i][j] = __builtin_amdgcn_mfma_f32_16x16x32_bf16(a[i], bb[j], acc1[i][j], 0, 0, 0);
    }
    __syncthreads();
#pragma unroll
    for (int i = 0; i < 2; ++i)
#pragma unroll
      for (int j = 0; j < 4; ++j)
#pragma unroll
        for (int v = 0; v < 4; ++v)
          at[(w * 32 + i * 16 + q * 4 + v) * 72 + j * 16 + r] = f2bf(acc1[i][j][v]);
    __syncthreads();
#pragma unroll
    for (int kk = 0; kk < 64; kk += 32) {
      bf16x8 a2[4], b2[4];
#pragma unroll
      for (int i = 0; i < 4; ++i)
        a2[i] = *(const bf16x8*)(const void*)(at + (wm2 + i * 16 + r) * 72 + kk + q * 8);
#pragma unroll
      for (int j = 0; j < 4; ++j)
        b2[j] = *(const bf16x8*)(wv + (size_t)(nq * 128 + wn2 + j * 16 + r) * 512 + hb + kk + q * 8);
#pragma unroll
      for (int i = 0; i < 4; ++i)
#pragma unroll
        for (int j = 0; j < 4; ++j)
          acc2[i][j] = __builtin_amdgcn_mfma_f32_16x16x32_bf16(a2[i], b2[j], acc2[i][j], 0, 0, 0);
    }
  }
#pragma unroll
  for (int i = 0; i < 4; ++i)
#pragma unroll
    for (int j = 0; j < 4; ++j)
#pragma unroll
      for (int v = 0; v < 4; ++v)
        MT[(size_t)b * 262144 + (size_t)(mq * 128 + wm2 + i * 16 + q * 4 + v) * 512 +
           nq * 128 + wn2 + j * 16 + r] = f2bf(acc2[i][j][v]);
}

// ---------------------------------------------------------------------------
// K6: out_b = Xn_b @ MT_b^T  (verbatim R0 gemm_v structure: 128x128 tile,
// 256 threads, 34 KB LDS, two-phase f32 bounce). 1024 blocks = 4/CU.
// ---------------------------------------------------------------------------
__global__ __launch_bounds__(256) void final_k(const ushort_t* __restrict__ xn,
                                               const ushort_t* __restrict__ MT,
                                               float* __restrict__ out) {
  __shared__ __align__(16) ushort_t sm[17408];   // staging 2x8192; bounce [64][132] f32
  ushort_t* As = sm;
  ushort_t* Bs = sm + 8192;
  float* Cb = (float*)sm;
  const int tid = threadIdx.x;
  const int lane = tid & 63;
  const int wave = tid >> 6;

  const int flat = blockIdx.x;   // 1024: xcd = b
  const int b = flat & 7;
  const int local = flat >> 3;   // 0..127
  const int mt = local >> 2, nt = local & 3;
  const int m0 = mt * 128, n0 = nt * 128;
  const size_t abase = (size_t)b * NSEQ;
  const ushort_t* BT = MT + (size_t)b * 262144;

  const int wm = (wave >> 1) * 64;
  const int wn = (wave & 1) * 64;
  const int srow = lane >> 3;
  const int scol = ((lane & 7) ^ srow) * 16;
  const int r = lane & 15, q = lane >> 4;

  f32x4 acc[4][4] = {};

  for (int k0 = 0; k0 < NDIM; k0 += 64) {
    __syncthreads();
#pragma unroll
    for (int c = 0; c < 4; ++c) {
      int chunk = wave * 4 + c;
      int row = chunk * 8 + srow;
      gload_lds16((const char*)(xn + (abase + m0 + row) * NDIM + k0) + scol,
                  (char*)As + chunk * 1024);
      gload_lds16((const char*)(BT + (size_t)(n0 + row) * 512 + k0) + scol,
                  (char*)Bs + chunk * 1024);
    }
    __syncthreads();
#pragma unroll
    for (int kk = 0; kk < 64; kk += 32) {
      const int kb = (kk >> 3) + q;
      bf16x8 af[4], bfr[4];
#pragma unroll
      for (int i = 0; i < 4; ++i) {
        int row = wm + i * 16 + r;
        af[i] = *(const bf16x8*)(const void*)(As + row * 64 + ((kb ^ (row & 7)) << 3));
      }
#pragma unroll
      for (int j = 0; j < 4; ++j) {
        int row = wn + j * 16 + r;
        bfr[j] = *(const bf16x8*)(const void*)(Bs + row * 64 + ((kb ^ (row & 7)) << 3));
      }
#pragma unroll
      for (int i = 0; i < 4; ++i)
#pragma unroll
        for (int j = 0; j < 4; ++j)
          acc[i][j] = __builtin_amdgcn_mfma_f32_16x16x32_bf16(af[i], bfr[j], acc[i][j], 0, 0, 0);
    }
  }
  // two-phase f32 LDS-bounce epilogue: [64][132] f32 per phase
#pragma unroll
  for (int p = 0; p < 2; ++p) {
    __syncthreads();
    if (wm == p * 64) {
#pragma unroll
      for (int i = 0; i < 4; ++i)
#pragma unroll
        for (int j = 0; j < 4; ++j)
#pragma unroll
          for (int v = 0; v < 4; ++v)
            Cb[(i * 16 + q * 4 + v) * 132 + wn + j * 16 + r] = acc[i][j][v];
    }
    __syncthreads();
#pragma unroll
    for (int i = 0; i < 8; ++i) {
      int row = (tid >> 3) + 32 * (i & 1);
      int col = (tid & 7) * 4 + (i >> 1) * 32;
      f32x4 val = *(const f32x4*)(Cb + row * 132 + col);
      *(f32x4*)(out + (abase + m0 + p * 64 + row) * NDIM + n0 + col) = val;
    }
  }
}

extern "C" void kernel_launch(void* const* d_in, const int* in_sizes, int n_in,
                              void* d_out, int out_size, void* d_ws, size_t ws_size,
                              hipStream_t stream) {
  (void)in_sizes; (void)n_in; (void)out_size; (void)ws_size;
  const float* x     = (const float*)d_in[0];
  const float* gamma = (const float*)d_in[1];
  const float* w_qkv = (const float*)d_in[2];
  const float* temp  = (const float*)d_in[3];
  const float* w_out = (const float*)d_in[4];
  float* out = (float*)d_out;
  char* ws = (char*)d_ws;

  // workspace layout (~86.5 MB):
  ushort_t* xn    = (ushort_t*)ws;                              // 32 MB
  ushort_t* xnTb  = (ushort_t*)(ws + (size_t)33554432);         // 32 MB (blocked)
  float*    S     = (float*)   (ws + (size_t)67108864);         // 8 MB f32
  ushort_t* PT    = (ushort_t*)(ws + (size_t)75497472);         // 8 MB
  ushort_t* MT    = (ushort_t*)(ws + (size_t)83886080);         // 4 MB
  ushort_t* attnT = (ushort_t*)(ws + (size_t)88080384);         // 0.5 MB
  ushort_t* wqkT  = (ushort_t*)(ws + (size_t)88604672);         // 1 MB
  ushort_t* woutT = (ushort_t*)(ws + (size_t)89653248);         // 0.5 MB
  ushort_t* wv    = (ushort_t*)(ws + (size_t)90177536);         // 0.5 MB

  prep_rms_k<<<9600, 256, 0, stream>>>(x, gamma, xn, w_qkv, w_out, wqkT, woutT, wv, S);
  xnt_k<<<4096, 256, 0, stream>>>(xn, xnTb);
  syrk_k<<<512, 256, 0, stream>>>(xnTb, S);
  pt_k<<<256, 256, 0, stream>>>(wqkT, S, PT);
  gsm_k<<<64, 256, 0, stream>>>(wqkT, PT, temp, attnT);
  atmt_k<<<128, 256, 0, stream>>>(woutT, attnT, wv, MT);
  final_k<<<1024, 256, 0, stream>>>(xn, MT, out);
}

// Round 9
// 248.037 us; speedup vs baseline: 1.1185x; 1.1185x over previous
//
#include <hip/hip_runtime.h>
#include <stdint.h>

#define NDIM 512
#define HEADS 8
#define DHEAD 64
#define NSEQ 4096
#define BATCH 8
#define ROWS (BATCH * NSEQ)   // 32768
#define QKVN (3 * NDIM)       // 1536
#define QKN 1024              // Q,K only

typedef unsigned short ushort_t;
typedef __bf16 bf16x8 __attribute__((ext_vector_type(8)));
typedef float f32x4 __attribute__((ext_vector_type(4)));
typedef unsigned short u16x8 __attribute__((ext_vector_type(8)));
typedef unsigned short u16x4 __attribute__((ext_vector_type(4)));

__device__ __forceinline__ ushort_t f2bf(float f) {
  union { float f; uint32_t u; } v; v.f = f;
  uint32_t r = (v.u + 0x7FFFu + ((v.u >> 16) & 1u)) >> 16;
  return (ushort_t)r;
}
__device__ __forceinline__ float bf2f(ushort_t h) {
  union { uint32_t u; float f; } v; v.u = ((uint32_t)h) << 16;
  return v.f;
}

__device__ __forceinline__ void gload_lds16(const void* g, void* l) {
  __builtin_amdgcn_global_load_lds(
      (__attribute__((address_space(1))) void*)(g),
      (__attribute__((address_space(3))) void*)(l), 16, 0, 0);
}

// ---------------------------------------------------------------------------
// K1: fused prep. Grid (256 threads each):
//   [0,8192)       rmsnorm (4 rows/block) -> xn bf16
//   [8192,8704)    wqkvT transpose: w_qkv cols 0..1023 -> wqkvT[1024][512]
//   [8704,8960)    woutT transpose: w_out -> woutT[512][512]
//   [8960,9088)    wv cast: w_qkv cols 1024..1535 -> wv[512][512] bf16
// ---------------------------------------------------------------------------
__global__ __launch_bounds__(256) void prep_rms_k(const float* __restrict__ x,
                                                  const float* __restrict__ gamma,
                                                  ushort_t* __restrict__ xn,
                                                  const float* __restrict__ w_qkv,
                                                  const float* __restrict__ w_out,
                                                  ushort_t* __restrict__ wqkvT,
                                                  ushort_t* __restrict__ woutT,
                                                  ushort_t* __restrict__ wv) {
  __shared__ float tile[32][33];
  int bid = blockIdx.x;
  int t = threadIdx.x;
  if (bid < 8192) {
    int wave = t >> 6, lane = t & 63;
    size_t row = (size_t)bid * 4 + wave;
    const float4* xr = (const float4*)(x + row * NDIM);
    float4 v0 = xr[lane * 2], v1 = xr[lane * 2 + 1];
    float s = v0.x*v0.x + v0.y*v0.y + v0.z*v0.z + v0.w*v0.w
            + v1.x*v1.x + v1.y*v1.y + v1.z*v1.z + v1.w*v1.w;
#pragma unroll
    for (int off = 32; off; off >>= 1) s += __shfl_xor(s, off, 64);
    float scale = 22.627416997969522f / fmaxf(sqrtf(s), 1e-12f);
    const float4* gr = (const float4*)gamma;
    float4 g0 = gr[lane * 2], g1 = gr[lane * 2 + 1];
    u16x8 o;
    o[0] = f2bf(v0.x * scale * g0.x);
    o[1] = f2bf(v0.y * scale * g0.y);
    o[2] = f2bf(v0.z * scale * g0.z);
    o[3] = f2bf(v0.w * scale * g0.w);
    o[4] = f2bf(v1.x * scale * g1.x);
    o[5] = f2bf(v1.y * scale * g1.y);
    o[6] = f2bf(v1.z * scale * g1.z);
    o[7] = f2bf(v1.w * scale * g1.w);
    *(u16x8*)(xn + row * NDIM + lane * 8) = o;
  } else if (bid < 8960) {
    // transpose+cast 32x32 tiles
    int id = bid - 8192;
    const float* src;
    ushort_t* dst;
    int srcStride, ni, ki;
    if (id < 512) { ni = id & 31; ki = id >> 5; src = w_qkv; dst = wqkvT; srcStride = QKVN; }
    else { id -= 512; ni = id & 15; ki = id >> 4; src = w_out; dst = woutT; srcStride = NDIM; }
    int tr = t >> 3;
    int tc = (t & 7) * 4;
    float4 v = *(const float4*)(src + (size_t)(ki * 32 + tr) * srcStride + ni * 32 + tc);
    tile[tr][tc] = v.x; tile[tr][tc + 1] = v.y; tile[tr][tc + 2] = v.z; tile[tr][tc + 3] = v.w;
    __syncthreads();
    u16x4 o;
    o[0] = f2bf(tile[tc + 0][tr]);
    o[1] = f2bf(tile[tc + 1][tr]);
    o[2] = f2bf(tile[tc + 2][tr]);
    o[3] = f2bf(tile[tc + 3][tr]);
    *(u16x4*)(dst + (size_t)(ni * 32 + tr) * NDIM + ki * 32 + tc) = o;
  } else {
    // wv cast: wv[c][j] = bf16(w_qkv[c][1024 + j])
    int id = bid - 8960;
    int f = id * 2048 + t * 8;
    int c = f >> 9, j = f & 511;
    float4 u0 = *(const float4*)(w_qkv + (size_t)c * QKVN + 1024 + j);
    float4 u1 = *(const float4*)(w_qkv + (size_t)c * QKVN + 1024 + j + 4);
    u16x8 o;
    o[0] = f2bf(u0.x); o[1] = f2bf(u0.y); o[2] = f2bf(u0.z); o[3] = f2bf(u0.w);
    o[4] = f2bf(u1.x); o[5] = f2bf(u1.y); o[6] = f2bf(u1.z); o[7] = f2bf(u1.w);
    *(u16x8*)(wv + (size_t)c * 512 + j) = o;
  }
}

// ---------------------------------------------------------------------------
// K2: QK GEMM (R0-verified structure): qk = xn[32768,512] @ wqkvT[1024,512]^T.
// 128x128 tile, 256 threads, XOR-swizzled staging, bf16 LDS-bounce epilogue.
// 2048 blocks, XCD-aware M-stripes.
// ---------------------------------------------------------------------------
__global__ __launch_bounds__(256) void gemm_qk(const ushort_t* __restrict__ A,
                                               const ushort_t* __restrict__ BT,
                                               ushort_t* __restrict__ C) {
  __shared__ ushort_t sm[17408];           // staging 2x8192; bounce [128][136]
  ushort_t* As = sm;
  ushort_t* Bs = sm + 8192;
  const int tid = threadIdx.x;
  const int lane = tid & 63;
  const int wave = tid >> 6;

  const int flat = blockIdx.x;             // 2048 blocks, NT=8
  const int xcd = flat & 7;
  const int idx = flat >> 3;               // 0..255
  const int local_m = idx >> 3;            // 0..31
  const int n_t = idx & 7;                 // 0..7
  const int m0 = (xcd * 32 + local_m) * 128;
  const int n0 = n_t * 128;

  const int wm = (wave >> 1) * 64;
  const int wn = (wave & 1) * 64;
  const int srow = lane >> 3;
  const int scol = ((lane & 7) ^ srow) * 16;
  const int r = lane & 15, q = lane >> 4;

  f32x4 acc[4][4] = {};

  for (int k0 = 0; k0 < NDIM; k0 += 64) {
    __syncthreads();
#pragma unroll
    for (int c = 0; c < 4; ++c) {
      int chunk = wave * 4 + c;
      int row = chunk * 8 + srow;
      gload_lds16((const char*)(A + (size_t)(m0 + row) * NDIM + k0) + scol,
                  (char*)As + chunk * 1024);
      gload_lds16((const char*)(BT + (size_t)(n0 + row) * NDIM + k0) + scol,
                  (char*)Bs + chunk * 1024);
    }
    __syncthreads();
#pragma unroll
    for (int kk = 0; kk < 64; kk += 32) {
      const int kb = (kk >> 3) + q;
      bf16x8 af[4], bfr[4];
#pragma unroll
      for (int i = 0; i < 4; ++i) {
        int row = wm + i * 16 + r;
        af[i] = *(const bf16x8*)(const void*)(As + row * 64 + ((kb ^ (row & 7)) << 3));
      }
#pragma unroll
      for (int j = 0; j < 4; ++j) {
        int row = wn + j * 16 + r;
        bfr[j] = *(const bf16x8*)(const void*)(Bs + row * 64 + ((kb ^ (row & 7)) << 3));
      }
#pragma unroll
      for (int i = 0; i < 4; ++i)
#pragma unroll
        for (int j = 0; j < 4; ++j)
          acc[i][j] = __builtin_amdgcn_mfma_f32_16x16x32_bf16(af[i], bfr[j], acc[i][j], 0, 0, 0);
    }
  }
  // LDS-bounce epilogue: [128][136] bf16
  __syncthreads();
#pragma unroll
  for (int i = 0; i < 4; ++i)
#pragma unroll
    for (int j = 0; j < 4; ++j)
#pragma unroll
      for (int v = 0; v < 4; ++v)
        sm[(wm + i * 16 + q * 4 + v) * 136 + wn + j * 16 + r] = f2bf(acc[i][j][v]);
  __syncthreads();
#pragma unroll
  for (int i = 0; i < 8; ++i) {
    int row = (tid >> 4) + 16 * i;
    int colB = (tid & 15) * 16;
    u16x8 val = *(const u16x8*)((const char*)sm + row * 272 + colB);
    *(u16x8*)((char*)(C + (size_t)(m0 + row) * QKN + n0) + colB) = val;
  }
}

// ---------------------------------------------------------------------------
// K3: gram partial (R0-verified, stride 1536->1024):
// pG[bh][chunk] += sum_n Q[n,d]K[n,e], + col sumsq into pSq.
// ---------------------------------------------------------------------------
__global__ __launch_bounds__(256) void gram_k(const ushort_t* __restrict__ qk,
                                              float* __restrict__ pG,
                                              float* __restrict__ pSq) {
  int chunk = blockIdx.x;  // 0..7
  int bh = blockIdx.y;     // 0..63
  int b = bh >> 3, h = bh & 7;
  __shared__ ushort_t Qt[64 * 72];
  __shared__ ushort_t Kt[64 * 72];
  __shared__ float sq[128];
  int tid = threadIdx.x, lane = tid & 63, wave = tid >> 6;
  int nl = tid >> 2;
  int dp = (tid & 3) * 16;
  int r = lane & 15, q = lane >> 4;
  float aq[16] = {}, ak[16] = {};
  f32x4 acc[4] = {};
  size_t base_row = ((size_t)b * NSEQ + (size_t)chunk * 512) * QKN + (size_t)h * DHEAD;
  int swz_n = ((nl >> 3) & 7);
  int c_lo = (nl & 7) | (((swz_n ^ (dp >> 3)) & 7) << 3);
  int c_hi = (nl & 7) | (((swz_n ^ ((dp >> 3) + 1)) & 7) << 3);
  ushort_t* qlo = Qt + dp * 72 + c_lo;
  ushort_t* qhi = Qt + (dp + 8) * 72 + c_hi;
  ushort_t* klo = Kt + dp * 72 + c_lo;
  ushort_t* khi = Kt + (dp + 8) * 72 + c_hi;

  for (int sc = 0; sc < 8; ++sc) {
    __syncthreads();
    size_t g = base_row + (size_t)(sc * 64 + nl) * QKN;
    u16x8 qv0 = *(const u16x8*)(qk + g + dp);
    u16x8 qv1 = *(const u16x8*)(qk + g + dp + 8);
    u16x8 kv0 = *(const u16x8*)(qk + g + 512 + dp);
    u16x8 kv1 = *(const u16x8*)(qk + g + 512 + dp + 8);
#pragma unroll
    for (int i = 0; i < 8; ++i) {
      float fq = bf2f(qv0[i]); aq[i] += fq * fq;       qlo[i * 72] = qv0[i];
      float fq2 = bf2f(qv1[i]); aq[8 + i] += fq2 * fq2; qhi[i * 72] = qv1[i];
      float fk = bf2f(kv0[i]); ak[i] += fk * fk;       klo[i * 72] = kv0[i];
      float fk2 = bf2f(kv1[i]); ak[8 + i] += fk2 * fk2; khi[i * 72] = kv1[i];
    }
    __syncthreads();
#pragma unroll
    for (int ks = 0; ks < 64; ks += 32) {
      int kb = (ks >> 3) + q;
      int m = wave * 16 + r;
      bf16x8 a = *(const bf16x8*)(const void*)(Qt + m * 72 + (((kb ^ (m >> 3)) & 7) << 3));
#pragma unroll
      for (int j = 0; j < 4; ++j) {
        int e = j * 16 + r;
        bf16x8 bb = *(const bf16x8*)(const void*)(Kt + e * 72 + (((kb ^ (e >> 3)) & 7) << 3));
        acc[j] = __builtin_amdgcn_mfma_f32_16x16x32_bf16(a, bb, acc[j], 0, 0, 0);
      }
    }
  }
  size_t gbase = ((size_t)bh * 8 + chunk) * 4096;
#pragma unroll
  for (int j = 0; j < 4; ++j)
#pragma unroll
    for (int v = 0; v < 4; ++v)
      pG[gbase + (size_t)(wave * 16 + q * 4 + v) * 64 + j * 16 + r] = acc[j][v];
  if (tid < 128) sq[tid] = 0.f;
  __syncthreads();
#pragma unroll
  for (int i = 0; i < 16; ++i) {
    atomicAdd(&sq[dp + i], aq[i]);
    atomicAdd(&sq[64 + dp + i], ak[i]);
  }
  __syncthreads();
  if (tid < 128) pSq[((size_t)bh * 8 + chunk) * 128 + tid] = sq[tid];
}

// ---------------------------------------------------------------------------
// K4: fused softmax + w2t (R3-verified): each block recomputes softmax(bh)
// into swizzled LDS; W2T[b][c'][h*64+e] = sum_d woutT[c'][h*64+d]*attn[e][d].
// ---------------------------------------------------------------------------
__global__ __launch_bounds__(256) void smax_w2t_k(const float* __restrict__ pG,
                                                  const float* __restrict__ pSq,
                                                  const float* __restrict__ temp,
                                                  const ushort_t* __restrict__ woutT,
                                                  ushort_t* __restrict__ W2T) {
  int mq = blockIdx.x;      // 0..3 (128 rows of c' each)
  int bh = blockIdx.y;      // 0..63
  int b = bh >> 3, h = bh & 7;
  __shared__ ushort_t at[64 * 64];   // attn[e][d], chunk-XOR swizzled
  __shared__ float kn[64];
  int t = threadIdx.x;

  {
    int d = t >> 2;
    int eg = (t & 3) * 16;
    if (t < 64) {
      float sk = 0.f;
      for (int c = 0; c < 8; ++c) sk += pSq[((size_t)bh * 8 + c) * 128 + 64 + t];
      kn[t] = fmaxf(sqrtf(sk), 1e-12f);
    }
    float sq = 0.f;
    for (int c = 0; c < 8; ++c) sq += pSq[((size_t)bh * 8 + c) * 128 + d];
    float qn = fmaxf(sqrtf(sq), 1e-12f);
    __syncthreads();
    float scale = 8.0f * expf(temp[h]) / qn;
    float row[16];
#pragma unroll
    for (int k = 0; k < 16; ++k) row[k] = 0.f;
    for (int c = 0; c < 8; ++c) {
      const float4* src = (const float4*)(pG + ((size_t)bh * 8 + c) * 4096 + d * 64 + eg);
#pragma unroll
      for (int k4 = 0; k4 < 4; ++k4) {
        float4 v = src[k4];
        row[k4 * 4 + 0] += v.x; row[k4 * 4 + 1] += v.y;
        row[k4 * 4 + 2] += v.z; row[k4 * 4 + 3] += v.w;
      }
    }
#pragma unroll
    for (int k = 0; k < 16; ++k) row[k] = row[k] * scale / kn[eg + k];
    float mx = -1e30f;
#pragma unroll
    for (int k = 0; k < 16; ++k) mx = fmaxf(mx, row[k]);
    mx = fmaxf(mx, __shfl_xor(mx, 1, 64));
    mx = fmaxf(mx, __shfl_xor(mx, 2, 64));
    float s = 0.f;
#pragma unroll
    for (int k = 0; k < 16; ++k) { row[k] = expf(row[k] - mx); s += row[k]; }
    s += __shfl_xor(s, 1, 64);
    s += __shfl_xor(s, 2, 64);
    float inv = 1.0f / s;
#pragma unroll
    for (int k = 0; k < 16; ++k) {
      int e = eg + k;
      at[e * 64 + ((d & 7) | ((((d >> 3) ^ e) & 7) << 3))] = f2bf(row[k] * inv);
    }
  }
  __syncthreads();

  int lane = t & 63, wave = t >> 6;
  int r = lane & 15, q = lane >> 4;
  int mbase = mq * 128 + wave * 32;
  f32x4 acc[2][4] = {};
#pragma unroll
  for (int kk = 0; kk < 64; kk += 32) {
    bf16x8 a[2], bb[4];
#pragma unroll
    for (int mf = 0; mf < 2; ++mf)
      a[mf] = *(const bf16x8*)(woutT + (size_t)(mbase + mf * 16 + r) * NDIM + h * 64 + kk + q * 8);
#pragma unroll
    for (int nf = 0; nf < 4; ++nf) {
      int e = nf * 16 + r;
      int c = (kk >> 3) + q;
      bb[nf] = *(const bf16x8*)(const void*)(at + e * 64 + (((c ^ e) & 7) << 3));
    }
#pragma unroll
    for (int mf = 0; mf < 2; ++mf)
#pragma unroll
      for (int nf = 0; nf < 4; ++nf)
        acc[mf][nf] = __builtin_amdgcn_mfma_f32_16x16x32_bf16(a[mf], bb[nf], acc[mf][nf], 0, 0, 0);
  }
#pragma unroll
  for (int mf = 0; mf < 2; ++mf)
#pragma unroll
    for (int nf = 0; nf < 4; ++nf)
#pragma unroll
      for (int v = 0; v < 4; ++v)
        W2T[(size_t)b * 262144 + (size_t)(mbase + mf * 16 + q * 4 + v) * NDIM +
            h * 64 + nf * 16 + r] = f2bf(acc[mf][nf][v]);
}

// ---------------------------------------------------------------------------
// K5: MT[b][c'][c] = sum_j W2T[b][c'][j] * wv[c][j]  (tiny 512^3 GEMM/batch,
// pt_k-verified structure: 128x128 tile, both operands gload-staged).
// ---------------------------------------------------------------------------
__global__ __launch_bounds__(256) void mt_k(const ushort_t* __restrict__ W2T,
                                            const ushort_t* __restrict__ wv,
                                            ushort_t* __restrict__ MT) {
  __shared__ __align__(16) ushort_t As[8192];   // [128][64] swizzled
  __shared__ __align__(16) ushort_t Bs[8192];
  const int flat = blockIdx.x;        // 128 = b(8) x mt(4) x nt(4)
  const int b = flat & 7;
  const int local = flat >> 3;        // 0..15
  const int mt = local >> 2, nt = local & 3;
  const int m0 = mt * 128, n0 = nt * 128;
  const int tid = threadIdx.x;
  const int lane = tid & 63, wave = tid >> 6;
  const int srow = lane >> 3;
  const int scol = ((lane & 7) ^ srow) * 16;
  const int r = lane & 15, q = lane >> 4;
  const int wm = (wave >> 1) * 64, wn = (wave & 1) * 64;
  const ushort_t* Ab = W2T + (size_t)b * 262144;

  f32x4 acc[4][4] = {};
  for (int k0 = 0; k0 < 512; k0 += 64) {
    __syncthreads();
#pragma unroll
    for (int c = 0; c < 4; ++c) {
      int g = wave * 4 + c;
      gload_lds16((const char*)(Ab + (size_t)(m0 + g * 8 + srow) * 512 + k0) + scol,
                  (char*)(As + g * 512));
      gload_lds16((const char*)(wv + (size_t)(n0 + g * 8 + srow) * 512 + k0) + scol,
                  (char*)(Bs + g * 512));
    }
    __syncthreads();
#pragma unroll
    for (int ph = 0; ph < 2; ++ph) {
      const int kb = ph * 4 + q;
      bf16x8 af[4], bfr[4];
#pragma unroll
      for (int i = 0; i < 4; ++i) {
        int row = wm + i * 16 + r;
        af[i] = *(const bf16x8*)(const void*)(As + row * 64 + ((kb ^ (row & 7)) << 3));
      }
#pragma unroll
      for (int j = 0; j < 4; ++j) {
        int row = wn + j * 16 + r;
        bfr[j] = *(const bf16x8*)(const void*)(Bs + row * 64 + ((kb ^ (row & 7)) << 3));
      }
#pragma unroll
      for (int i = 0; i < 4; ++i)
#pragma unroll
        for (int j = 0; j < 4; ++j)
          acc[i][j] = __builtin_amdgcn_mfma_f32_16x16x32_bf16(af[i], bfr[j], acc[i][j], 0, 0, 0);
    }
  }
  ushort_t* dst = MT + (size_t)b * 262144;
#pragma unroll
  for (int i = 0; i < 4; ++i)
#pragma unroll
    for (int j = 0; j < 4; ++j)
#pragma unroll
      for (int v = 0; v < 4; ++v)
        dst[(size_t)(m0 + wm + i * 16 + q * 4 + v) * 512 + n0 + wn + j * 16 + r] =
            f2bf(acc[i][j][v]);
}

// ---------------------------------------------------------------------------
// K6: out_b = Xn_b @ MT_b^T  (R8-verified: 128x128 tile, 256 threads,
// two-phase f32 bounce). 1024 blocks, xcd = b.
// ---------------------------------------------------------------------------
__global__ __launch_bounds__(256) void final_k(const ushort_t* __restrict__ xn,
                                               const ushort_t* __restrict__ MT,
                                               float* __restrict__ out) {
  __shared__ __align__(16) ushort_t sm[17408];   // staging 2x8192; bounce [64][132] f32
  ushort_t* As = sm;
  ushort_t* Bs = sm + 8192;
  float* Cb = (float*)sm;
  const int tid = threadIdx.x;
  const int lane = tid & 63;
  const int wave = tid >> 6;

  const int flat = blockIdx.x;   // 1024: xcd = b
  const int b = flat & 7;
  const int local = flat >> 3;   // 0..127
  const int mt = local >> 2, nt = local & 3;
  const int m0 = mt * 128, n0 = nt * 128;
  const size_t abase = (size_t)b * NSEQ;
  const ushort_t* BT = MT + (size_t)b * 262144;

  const int wm = (wave >> 1) * 64;
  const int wn = (wave & 1) * 64;
  const int srow = lane >> 3;
  const int scol = ((lane & 7) ^ srow) * 16;
  const int r = lane & 15, q = lane >> 4;

  f32x4 acc[4][4] = {};

  for (int k0 = 0; k0 < NDIM; k0 += 64) {
    __syncthreads();
#pragma unroll
    for (int c = 0; c < 4; ++c) {
      int chunk = wave * 4 + c;
      int row = chunk * 8 + srow;
      gload_lds16((const char*)(xn + (abase + m0 + row) * NDIM + k0) + scol,
                  (char*)As + chunk * 1024);
      gload_lds16((const char*)(BT + (size_t)(n0 + row) * 512 + k0) + scol,
                  (char*)Bs + chunk * 1024);
    }
    __syncthreads();
#pragma unroll
    for (int kk = 0; kk < 64; kk += 32) {
      const int kb = (kk >> 3) + q;
      bf16x8 af[4], bfr[4];
#pragma unroll
      for (int i = 0; i < 4; ++i) {
        int row = wm + i * 16 + r;
        af[i] = *(const bf16x8*)(const void*)(As + row * 64 + ((kb ^ (row & 7)) << 3));
      }
#pragma unroll
      for (int j = 0; j < 4; ++j) {
        int row = wn + j * 16 + r;
        bfr[j] = *(const bf16x8*)(const void*)(Bs + row * 64 + ((kb ^ (row & 7)) << 3));
      }
#pragma unroll
      for (int i = 0; i < 4; ++i)
#pragma unroll
        for (int j = 0; j < 4; ++j)
          acc[i][j] = __builtin_amdgcn_mfma_f32_16x16x32_bf16(af[i], bfr[j], acc[i][j], 0, 0, 0);
    }
  }
  // two-phase f32 LDS-bounce epilogue: [64][132] f32 per phase
#pragma unroll
  for (int p = 0; p < 2; ++p) {
    __syncthreads();
    if (wm == p * 64) {
#pragma unroll
      for (int i = 0; i < 4; ++i)
#pragma unroll
        for (int j = 0; j < 4; ++j)
#pragma unroll
          for (int v = 0; v < 4; ++v)
            Cb[(i * 16 + q * 4 + v) * 132 + wn + j * 16 + r] = acc[i][j][v];
    }
    __syncthreads();
#pragma unroll
    for (int i = 0; i < 8; ++i) {
      int row = (tid >> 3) + 32 * (i & 1);
      int col = (tid & 7) * 4 + (i >> 1) * 32;
      f32x4 val = *(const f32x4*)(Cb + row * 132 + col);
      *(f32x4*)(out + (abase + m0 + p * 64 + row) * NDIM + n0 + col) = val;
    }
  }
}

extern "C" void kernel_launch(void* const* d_in, const int* in_sizes, int n_in,
                              void* d_out, int out_size, void* d_ws, size_t ws_size,
                              hipStream_t stream) {
  (void)in_sizes; (void)n_in; (void)out_size; (void)ws_size;
  const float* x     = (const float*)d_in[0];
  const float* gamma = (const float*)d_in[1];
  const float* w_qkv = (const float*)d_in[2];
  const float* temp  = (const float*)d_in[3];
  const float* w_out = (const float*)d_in[4];
  float* out = (float*)d_out;
  char* ws = (char*)d_ws;

  // workspace layout (~114.3 MB):
  ushort_t* qk    = (ushort_t*)ws;                              // 64 MB [32768][1024]
  ushort_t* xn    = (ushort_t*)(ws + (size_t)67108864);         // 32 MB
  float*    pG    = (float*)   (ws + (size_t)100663296);        // 8 MB
  float*    pSq   = (float*)   (ws + (size_t)109051904);        // 256 KB
  ushort_t* W2T   = (ushort_t*)(ws + (size_t)109314048);        // 4 MB
  ushort_t* MT    = (ushort_t*)(ws + (size_t)113508352);        // 4 MB
  ushort_t* wqkvT = (ushort_t*)(ws + (size_t)117702656);        // 1 MB
  ushort_t* woutT = (ushort_t*)(ws + (size_t)118751232);        // 0.5 MB
  ushort_t* wv    = (ushort_t*)(ws + (size_t)119275520);        // 0.5 MB

  prep_rms_k<<<9088, 256, 0, stream>>>(x, gamma, xn, w_qkv, w_out, wqkvT, woutT, wv);
  gemm_qk<<<2048, 256, 0, stream>>>(xn, wqkvT, qk);
  gram_k<<<dim3(8, 64), 256, 0, stream>>>(qk, pG, pSq);
  smax_w2t_k<<<dim3(4, 64), 256, 0, stream>>>(pG, pSq, temp, woutT, W2T);
  mt_k<<<128, 256, 0, stream>>>(W2T, wv, MT);
  final_k<<<1024, 256, 0, stream>>>(xn, MT, out);
}

// Round 10
// 211.076 us; speedup vs baseline: 1.3143x; 1.1751x over previous
//
#include <hip/hip_runtime.h>
#include <stdint.h>

#define NDIM 512
#define HEADS 8
#define DHEAD 64
#define NSEQ 4096
#define BATCH 8
#define ROWS (BATCH * NSEQ)   // 32768
#define QKVN (3 * NDIM)       // 1536

typedef unsigned short ushort_t;
typedef __bf16 bf16x8 __attribute__((ext_vector_type(8)));
typedef float f32x4 __attribute__((ext_vector_type(4)));
typedef unsigned short u16x8 __attribute__((ext_vector_type(8)));
typedef unsigned short u16x4 __attribute__((ext_vector_type(4)));

__device__ __forceinline__ ushort_t f2bf(float f) {
  union { float f; uint32_t u; } v; v.f = f;
  uint32_t r = (v.u + 0x7FFFu + ((v.u >> 16) & 1u)) >> 16;
  return (ushort_t)r;
}
__device__ __forceinline__ float bf2f(ushort_t h) {
  union { uint32_t u; float f; } v; v.u = ((uint32_t)h) << 16;
  return v.f;
}

__device__ __forceinline__ void gload_lds16(const void* g, void* l) {
  __builtin_amdgcn_global_load_lds(
      (__attribute__((address_space(1))) void*)(g),
      (__attribute__((address_space(3))) void*)(l), 16, 0, 0);
}

// ---------------------------------------------------------------------------
// K1: fused prep. Grid (256 threads each):
//   [0,8192)       rmsnorm (4 rows/block) -> xn bf16
//   [8192,8704)    wqkvT transpose: w_qkv cols 0..1023 -> wqkvT[1024][512]
//   [8704,8960)    woutT transpose: w_out -> woutT[512][512]
//   [8960,9088)    wv cast: w_qkv cols 1024..1535 -> wv[512][512] bf16
//   [9088,9152)    zero Gf (1 MB f32)
//   [9152,9154)    zero pSq (32 KB f32)
// ---------------------------------------------------------------------------
__global__ __launch_bounds__(256) void prep_rms_k(const float* __restrict__ x,
                                                  const float* __restrict__ gamma,
                                                  ushort_t* __restrict__ xn,
                                                  const float* __restrict__ w_qkv,
                                                  const float* __restrict__ w_out,
                                                  ushort_t* __restrict__ wqkvT,
                                                  ushort_t* __restrict__ woutT,
                                                  ushort_t* __restrict__ wv,
                                                  float* __restrict__ Gf,
                                                  float* __restrict__ pSq) {
  __shared__ float tile[32][33];
  int bid = blockIdx.x;
  int t = threadIdx.x;
  if (bid < 8192) {
    int wave = t >> 6, lane = t & 63;
    size_t row = (size_t)bid * 4 + wave;
    const float4* xr = (const float4*)(x + row * NDIM);
    float4 v0 = xr[lane * 2], v1 = xr[lane * 2 + 1];
    float s = v0.x*v0.x + v0.y*v0.y + v0.z*v0.z + v0.w*v0.w
            + v1.x*v1.x + v1.y*v1.y + v1.z*v1.z + v1.w*v1.w;
#pragma unroll
    for (int off = 32; off; off >>= 1) s += __shfl_xor(s, off, 64);
    float scale = 22.627416997969522f / fmaxf(sqrtf(s), 1e-12f);
    const float4* gr = (const float4*)gamma;
    float4 g0 = gr[lane * 2], g1 = gr[lane * 2 + 1];
    u16x8 o;
    o[0] = f2bf(v0.x * scale * g0.x);
    o[1] = f2bf(v0.y * scale * g0.y);
    o[2] = f2bf(v0.z * scale * g0.z);
    o[3] = f2bf(v0.w * scale * g0.w);
    o[4] = f2bf(v1.x * scale * g1.x);
    o[5] = f2bf(v1.y * scale * g1.y);
    o[6] = f2bf(v1.z * scale * g1.z);
    o[7] = f2bf(v1.w * scale * g1.w);
    *(u16x8*)(xn + row * NDIM + lane * 8) = o;
  } else if (bid < 8960) {
    // transpose+cast 32x32 tiles
    int id = bid - 8192;
    const float* src;
    ushort_t* dst;
    int srcStride, ni, ki;
    if (id < 512) { ni = id & 31; ki = id >> 5; src = w_qkv; dst = wqkvT; srcStride = QKVN; }
    else { id -= 512; ni = id & 15; ki = id >> 4; src = w_out; dst = woutT; srcStride = NDIM; }
    int tr = t >> 3;
    int tc = (t & 7) * 4;
    float4 v = *(const float4*)(src + (size_t)(ki * 32 + tr) * srcStride + ni * 32 + tc);
    tile[tr][tc] = v.x; tile[tr][tc + 1] = v.y; tile[tr][tc + 2] = v.z; tile[tr][tc + 3] = v.w;
    __syncthreads();
    u16x4 o;
    o[0] = f2bf(tile[tc + 0][tr]);
    o[1] = f2bf(tile[tc + 1][tr]);
    o[2] = f2bf(tile[tc + 2][tr]);
    o[3] = f2bf(tile[tc + 3][tr]);
    *(u16x4*)(dst + (size_t)(ni * 32 + tr) * NDIM + ki * 32 + tc) = o;
  } else if (bid < 9088) {
    // wv cast: wv[c][j] = bf16(w_qkv[c][1024 + j])
    int id = bid - 8960;
    int f = id * 2048 + t * 8;
    int c = f >> 9, j = f & 511;
    float4 u0 = *(const float4*)(w_qkv + (size_t)c * QKVN + 1024 + j);
    float4 u1 = *(const float4*)(w_qkv + (size_t)c * QKVN + 1024 + j + 4);
    u16x8 o;
    o[0] = f2bf(u0.x); o[1] = f2bf(u0.y); o[2] = f2bf(u0.z); o[3] = f2bf(u0.w);
    o[4] = f2bf(u1.x); o[5] = f2bf(u1.y); o[6] = f2bf(u1.z); o[7] = f2bf(u1.w);
    *(u16x8*)(wv + (size_t)c * 512 + j) = o;
  } else if (bid < 9152) {
    int id = bid - 9088;   // 0..63: zero Gf (4096 f32 each)
    f32x4 z = {};
#pragma unroll
    for (int i = 0; i < 4; ++i)
      *(f32x4*)(Gf + (size_t)id * 4096 + i * 1024 + t * 4) = z;
  } else {
    int id = bid - 9152;   // 0..1: zero pSq (4096 f32 each)
    f32x4 z = {};
#pragma unroll
    for (int i = 0; i < 4; ++i)
      *(f32x4*)(pSq + (size_t)id * 4096 + i * 1024 + t * 4) = z;
  }
}

// ---------------------------------------------------------------------------
// K2: fused QK GEMM + gram epilogue. Per block (m-tile of 128 n-rows, head h):
// main loop = R0-verified 128x128 tile (cols: 64 Q-d | 64 K-e);
// epilogue: transposed bounce CbT[col][n] -> 16 MFMAs/wave G-partial
// (atomicAdd into Gf[bh]) + column sumsq (atomicAdd into pSq[bh]).
// Q,K are NEVER materialized to HBM.
// ---------------------------------------------------------------------------
__global__ __launch_bounds__(256) void gemm_qkg(const ushort_t* __restrict__ A,
                                                const ushort_t* __restrict__ BT,
                                                float* __restrict__ Gf,
                                                float* __restrict__ pSq) {
  __shared__ ushort_t sm[17408];           // staging 2x8192; bounce CbT [128][136]
  ushort_t* As = sm;
  ushort_t* Bs = sm + 8192;
  const int tid = threadIdx.x;
  const int lane = tid & 63;
  const int wave = tid >> 6;

  const int flat = blockIdx.x;             // 2048 blocks
  const int xcd = flat & 7;
  const int idx = flat >> 3;               // 0..255
  const int local_m = idx >> 3;            // 0..31
  const int h = idx & 7;                   // head
  const int m0 = (xcd * 32 + local_m) * 128;
  const int b = m0 >> 12;                  // m0 / 4096
  const int bh = b * 8 + h;

  const int wm = (wave >> 1) * 64;
  const int wn = (wave & 1) * 64;
  const int srow = lane >> 3;
  const int scol = ((lane & 7) ^ srow) * 16;
  const int r = lane & 15, q = lane >> 4;

  f32x4 acc[4][4] = {};

  for (int k0 = 0; k0 < NDIM; k0 += 64) {
    __syncthreads();
#pragma unroll
    for (int c = 0; c < 4; ++c) {
      int chunk = wave * 4 + c;
      int row = chunk * 8 + srow;
      // B row mapping: row<64 -> Q-head (wqkvT[h*64+row]); else K-head
      int brow = (row < 64) ? (h * 64 + row) : (512 + h * 64 + (row - 64));
      gload_lds16((const char*)(A + (size_t)(m0 + row) * NDIM + k0) + scol,
                  (char*)As + chunk * 1024);
      gload_lds16((const char*)(BT + (size_t)brow * NDIM + k0) + scol,
                  (char*)Bs + chunk * 1024);
    }
    __syncthreads();
#pragma unroll
    for (int kk = 0; kk < 64; kk += 32) {
      const int kb = (kk >> 3) + q;
      bf16x8 af[4], bfr[4];
#pragma unroll
      for (int i = 0; i < 4; ++i) {
        int row = wm + i * 16 + r;
        af[i] = *(const bf16x8*)(const void*)(As + row * 64 + ((kb ^ (row & 7)) << 3));
      }
#pragma unroll
      for (int j = 0; j < 4; ++j) {
        int row = wn + j * 16 + r;
        bfr[j] = *(const bf16x8*)(const void*)(Bs + row * 64 + ((kb ^ (row & 7)) << 3));
      }
#pragma unroll
      for (int i = 0; i < 4; ++i)
#pragma unroll
        for (int j = 0; j < 4; ++j)
          acc[i][j] = __builtin_amdgcn_mfma_f32_16x16x32_bf16(af[i], bfr[j], acc[i][j], 0, 0, 0);
    }
  }

  // ---- transposed bounce: CbT[col][n], col 0..63 = Q-d, 64..127 = K-e ----
  __syncthreads();
#pragma unroll
  for (int i = 0; i < 4; ++i)
#pragma unroll
    for (int j = 0; j < 4; ++j) {
      u16x4 o;
#pragma unroll
      for (int v = 0; v < 4; ++v) o[v] = f2bf(acc[i][j][v]);
      // acc[i][j][v] = C[n = wm+i*16+q*4+v][col = wn+j*16+r]
      *(u16x4*)(sm + (wn + j * 16 + r) * 136 + wm + i * 16 + q * 4) = o;
    }
  __syncthreads();

  // ---- G-partial: G[d][e] += sum_n Q^T[d][n]*K^T[e][n]; wave = d-tile ----
  {
    f32x4 g[4] = {};
#pragma unroll
    for (int kk = 0; kk < 128; kk += 32) {
      bf16x8 af = *(const bf16x8*)(const void*)(sm + (wave * 16 + r) * 136 + kk + q * 8);
#pragma unroll
      for (int j = 0; j < 4; ++j) {
        bf16x8 bfr = *(const bf16x8*)(const void*)(sm + (64 + j * 16 + r) * 136 + kk + q * 8);
        g[j] = __builtin_amdgcn_mfma_f32_16x16x32_bf16(af, bfr, g[j], 0, 0, 0);
      }
    }
    float* Gb = Gf + (size_t)bh * 4096;
#pragma unroll
    for (int j = 0; j < 4; ++j)
#pragma unroll
      for (int v = 0; v < 4; ++v)
        atomicAdd(&Gb[(wave * 16 + q * 4 + v) * 64 + j * 16 + r], g[j][v]);
  }

  // ---- column sumsq: pSq[bh][0..63]=Q-d, [64..127]=K-e ----
  {
    int row = tid & 127;       // CbT row = col of C
    int half = tid >> 7;       // n-half
    const ushort_t* p = sm + row * 136 + half * 64;
    float s = 0.f;
#pragma unroll
    for (int u = 0; u < 8; ++u) {
      u16x8 vls = *(const u16x8*)(p + u * 8);
#pragma unroll
      for (int k2 = 0; k2 < 8; ++k2) { float f = bf2f(vls[k2]); s += f * f; }
    }
    atomicAdd(&pSq[(size_t)bh * 128 + row], s);
  }
}

// ---------------------------------------------------------------------------
// K3: fused softmax + w2t: each block recomputes softmax(bh) from Gf/pSq
// into swizzled LDS; W2T[b][c'][h*64+e] = sum_d woutT[c'][h*64+d]*attn[e][d].
// ---------------------------------------------------------------------------
__global__ __launch_bounds__(256) void smax_w2t_k(const float* __restrict__ Gf,
                                                  const float* __restrict__ pSq,
                                                  const float* __restrict__ temp,
                                                  const ushort_t* __restrict__ woutT,
                                                  ushort_t* __restrict__ W2T) {
  int mq = blockIdx.x;      // 0..3 (128 rows of c' each)
  int bh = blockIdx.y;      // 0..63
  int b = bh >> 3, h = bh & 7;
  __shared__ ushort_t at[64 * 64];   // attn[e][d], chunk-XOR swizzled
  __shared__ float kn[64];
  int t = threadIdx.x;

  {
    int d = t >> 2;
    int eg = (t & 3) * 16;
    if (t < 64)
      kn[t] = fmaxf(sqrtf(pSq[(size_t)bh * 128 + 64 + t]), 1e-12f);
    float qn = fmaxf(sqrtf(pSq[(size_t)bh * 128 + d]), 1e-12f);
    __syncthreads();
    float scale = 8.0f * expf(temp[h]) / qn;
    float row[16];
    const float4* src = (const float4*)(Gf + (size_t)bh * 4096 + d * 64 + eg);
#pragma unroll
    for (int k4 = 0; k4 < 4; ++k4) {
      float4 v = src[k4];
      row[k4 * 4 + 0] = v.x; row[k4 * 4 + 1] = v.y;
      row[k4 * 4 + 2] = v.z; row[k4 * 4 + 3] = v.w;
    }
#pragma unroll
    for (int k = 0; k < 16; ++k) row[k] = row[k] * scale / kn[eg + k];
    float mx = -1e30f;
#pragma unroll
    for (int k = 0; k < 16; ++k) mx = fmaxf(mx, row[k]);
    mx = fmaxf(mx, __shfl_xor(mx, 1, 64));
    mx = fmaxf(mx, __shfl_xor(mx, 2, 64));
    float s = 0.f;
#pragma unroll
    for (int k = 0; k < 16; ++k) { row[k] = expf(row[k] - mx); s += row[k]; }
    s += __shfl_xor(s, 1, 64);
    s += __shfl_xor(s, 2, 64);
    float inv = 1.0f / s;
#pragma unroll
    for (int k = 0; k < 16; ++k) {
      int e = eg + k;
      at[e * 64 + ((d & 7) | ((((d >> 3) ^ e) & 7) << 3))] = f2bf(row[k] * inv);
    }
  }
  __syncthreads();

  int lane = t & 63, wave = t >> 6;
  int r = lane & 15, q = lane >> 4;
  int mbase = mq * 128 + wave * 32;
  f32x4 acc[2][4] = {};
#pragma unroll
  for (int kk = 0; kk < 64; kk += 32) {
    bf16x8 a[2], bb[4];
#pragma unroll
    for (int mf = 0; mf < 2; ++mf)
      a[mf] = *(const bf16x8*)(woutT + (size_t)(mbase + mf * 16 + r) * NDIM + h * 64 + kk + q * 8);
#pragma unroll
    for (int nf = 0; nf < 4; ++nf) {
      int e = nf * 16 + r;
      int c = (kk >> 3) + q;
      bb[nf] = *(const bf16x8*)(const void*)(at + e * 64 + (((c ^ e) & 7) << 3));
    }
#pragma unroll
    for (int mf = 0; mf < 2; ++mf)
#pragma unroll
      for (int nf = 0; nf < 4; ++nf)
        acc[mf][nf] = __builtin_amdgcn_mfma_f32_16x16x32_bf16(a[mf], bb[nf], acc[mf][nf], 0, 0, 0);
  }
#pragma unroll
  for (int mf = 0; mf < 2; ++mf)
#pragma unroll
    for (int nf = 0; nf < 4; ++nf)
#pragma unroll
      for (int v = 0; v < 4; ++v)
        W2T[(size_t)b * 262144 + (size_t)(mbase + mf * 16 + q * 4 + v) * NDIM +
            h * 64 + nf * 16 + r] = f2bf(acc[mf][nf][v]);
}

// ---------------------------------------------------------------------------
// K4: MT[b][c'][c] = sum_j W2T[b][c'][j] * wv[c][j]  (tiny 512^3 GEMM/batch)
// ---------------------------------------------------------------------------
__global__ __launch_bounds__(256) void mt_k(const ushort_t* __restrict__ W2T,
                                            const ushort_t* __restrict__ wv,
                                            ushort_t* __restrict__ MT) {
  __shared__ __align__(16) ushort_t As[8192];   // [128][64] swizzled
  __shared__ __align__(16) ushort_t Bs[8192];
  const int flat = blockIdx.x;        // 128 = b(8) x mt(4) x nt(4)
  const int b = flat & 7;
  const int local = flat >> 3;        // 0..15
  const int mt = local >> 2, nt = local & 3;
  const int m0 = mt * 128, n0 = nt * 128;
  const int tid = threadIdx.x;
  const int lane = tid & 63, wave = tid >> 6;
  const int srow = lane >> 3;
  const int scol = ((lane & 7) ^ srow) * 16;
  const int r = lane & 15, q = lane >> 4;
  const int wm = (wave >> 1) * 64, wn = (wave & 1) * 64;
  const ushort_t* Ab = W2T + (size_t)b * 262144;

  f32x4 acc[4][4] = {};
  for (int k0 = 0; k0 < 512; k0 += 64) {
    __syncthreads();
#pragma unroll
    for (int c = 0; c < 4; ++c) {
      int g = wave * 4 + c;
      gload_lds16((const char*)(Ab + (size_t)(m0 + g * 8 + srow) * 512 + k0) + scol,
                  (char*)(As + g * 512));
      gload_lds16((const char*)(wv + (size_t)(n0 + g * 8 + srow) * 512 + k0) + scol,
                  (char*)(Bs + g * 512));
    }
    __syncthreads();
#pragma unroll
    for (int ph = 0; ph < 2; ++ph) {
      const int kb = ph * 4 + q;
      bf16x8 af[4], bfr[4];
#pragma unroll
      for (int i = 0; i < 4; ++i) {
        int row = wm + i * 16 + r;
        af[i] = *(const bf16x8*)(const void*)(As + row * 64 + ((kb ^ (row & 7)) << 3));
      }
#pragma unroll
      for (int j = 0; j < 4; ++j) {
        int row = wn + j * 16 + r;
        bfr[j] = *(const bf16x8*)(const void*)(Bs + row * 64 + ((kb ^ (row & 7)) << 3));
      }
#pragma unroll
      for (int i = 0; i < 4; ++i)
#pragma unroll
        for (int j = 0; j < 4; ++j)
          acc[i][j] = __builtin_amdgcn_mfma_f32_16x16x32_bf16(af[i], bfr[j], acc[i][j], 0, 0, 0);
    }
  }
  ushort_t* dst = MT + (size_t)b * 262144;
#pragma unroll
  for (int i = 0; i < 4; ++i)
#pragma unroll
    for (int j = 0; j < 4; ++j)
#pragma unroll
      for (int v = 0; v < 4; ++v)
        dst[(size_t)(m0 + wm + i * 16 + q * 4 + v) * 512 + n0 + wn + j * 16 + r] =
            f2bf(acc[i][j][v]);
}

// ---------------------------------------------------------------------------
// K5: out_b = Xn_b @ MT_b^T  (R8/R9-verified: 128x128 tile, 256 threads,
// two-phase f32 bounce). 1024 blocks, xcd = b.
// ---------------------------------------------------------------------------
__global__ __launch_bounds__(256) void final_k(const ushort_t* __restrict__ xn,
                                               const ushort_t* __restrict__ MT,
                                               float* __restrict__ out) {
  __shared__ __align__(16) ushort_t sm[17408];   // staging 2x8192; bounce [64][132] f32
  ushort_t* As = sm;
  ushort_t* Bs = sm + 8192;
  float* Cb = (float*)sm;
  const int tid = threadIdx.x;
  const int lane = tid & 63;
  const int wave = tid >> 6;

  const int flat = blockIdx.x;   // 1024: xcd = b
  const int b = flat & 7;
  const int local = flat >> 3;   // 0..127
  const int mt = local >> 2, nt = local & 3;
  const int m0 = mt * 128, n0 = nt * 128;
  const size_t abase = (size_t)b * NSEQ;
  const ushort_t* BT = MT + (size_t)b * 262144;

  const int wm = (wave >> 1) * 64;
  const int wn = (wave & 1) * 64;
  const int srow = lane >> 3;
  const int scol = ((lane & 7) ^ srow) * 16;
  const int r = lane & 15, q = lane >> 4;

  f32x4 acc[4][4] = {};

  for (int k0 = 0; k0 < NDIM; k0 += 64) {
    __syncthreads();
#pragma unroll
    for (int c = 0; c < 4; ++c) {
      int chunk = wave * 4 + c;
      int row = chunk * 8 + srow;
      gload_lds16((const char*)(xn + (abase + m0 + row) * NDIM + k0) + scol,
                  (char*)As + chunk * 1024);
      gload_lds16((const char*)(BT + (size_t)(n0 + row) * 512 + k0) + scol,
                  (char*)Bs + chunk * 1024);
    }
    __syncthreads();
#pragma unroll
    for (int kk = 0; kk < 64; kk += 32) {
      const int kb = (kk >> 3) + q;
      bf16x8 af[4], bfr[4];
#pragma unroll
      for (int i = 0; i < 4; ++i) {
        int row = wm + i * 16 + r;
        af[i] = *(const bf16x8*)(const void*)(As + row * 64 + ((kb ^ (row & 7)) << 3));
      }
#pragma unroll
      for (int j = 0; j < 4; ++j) {
        int row = wn + j * 16 + r;
        bfr[j] = *(const bf16x8*)(const void*)(Bs + row * 64 + ((kb ^ (row & 7)) << 3));
      }
#pragma unroll
      for (int i = 0; i < 4; ++i)
#pragma unroll
        for (int j = 0; j < 4; ++j)
          acc[i][j] = __builtin_amdgcn_mfma_f32_16x16x32_bf16(af[i], bfr[j], acc[i][j], 0, 0, 0);
    }
  }
  // two-phase f32 LDS-bounce epilogue: [64][132] f32 per phase
#pragma unroll
  for (int p = 0; p < 2; ++p) {
    __syncthreads();
    if (wm == p * 64) {
#pragma unroll
      for (int i = 0; i < 4; ++i)
#pragma unroll
        for (int j = 0; j < 4; ++j)
#pragma unroll
          for (int v = 0; v < 4; ++v)
            Cb[(i * 16 + q * 4 + v) * 132 + wn + j * 16 + r] = acc[i][j][v];
    }
    __syncthreads();
#pragma unroll
    for (int i = 0; i < 8; ++i) {
      int row = (tid >> 3) + 32 * (i & 1);
      int col = (tid & 7) * 4 + (i >> 1) * 32;
      f32x4 val = *(const f32x4*)(Cb + row * 132 + col);
      *(f32x4*)(out + (abase + m0 + p * 64 + row) * NDIM + n0 + col) = val;
    }
  }
}

extern "C" void kernel_launch(void* const* d_in, const int* in_sizes, int n_in,
                              void* d_out, int out_size, void* d_ws, size_t ws_size,
                              hipStream_t stream) {
  (void)in_sizes; (void)n_in; (void)out_size; (void)ws_size;
  const float* x     = (const float*)d_in[0];
  const float* gamma = (const float*)d_in[1];
  const float* w_qkv = (const float*)d_in[2];
  const float* temp  = (const float*)d_in[3];
  const float* w_out = (const float*)d_in[4];
  float* out = (float*)d_out;
  char* ws = (char*)d_ws;

  // workspace layout (~45 MB):
  ushort_t* xn    = (ushort_t*)ws;                              // 32 MB
  float*    Gf    = (float*)   (ws + (size_t)33554432);         // 1 MB  [64 bh][4096]
  float*    pSq   = (float*)   (ws + (size_t)34603008);         // 32 KB [64 bh][128]
  ushort_t* W2T   = (ushort_t*)(ws + (size_t)34635776);         // 4 MB
  ushort_t* MT    = (ushort_t*)(ws + (size_t)38830080);         // 4 MB
  ushort_t* wqkvT = (ushort_t*)(ws + (size_t)43024384);         // 1 MB
  ushort_t* woutT = (ushort_t*)(ws + (size_t)44072960);         // 0.5 MB
  ushort_t* wv    = (ushort_t*)(ws + (size_t)44597248);         // 0.5 MB

  prep_rms_k<<<9154, 256, 0, stream>>>(x, gamma, xn, w_qkv, w_out, wqkvT, woutT, wv, Gf, pSq);
  gemm_qkg<<<2048, 256, 0, stream>>>(xn, wqkvT, Gf, pSq);
  smax_w2t_k<<<dim3(4, 64), 256, 0, stream>>>(Gf, pSq, temp, woutT, W2T);
  mt_k<<<128, 256, 0, stream>>>(W2T, wv, MT);
  final_k<<<1024, 256, 0, stream>>>(xn, MT, out);
}